// Round 5
// baseline (4478.229 us; speedup 1.0000x reference)
//
#include <hip/hip_runtime.h>

#define S    4096
#define CH   256
#define NB   8

#define BM   128
#define BN   128
#define CK   16
#define KSPLIT 8

#define NEG_INF (-3.402823466e38f)

// ---------------------------------------------------------------------------
// out[:, 0:512] = input  (runs AFTER argmax_gemm — that slab is GEMM scratch)
__global__ void copy_fl(const float* __restrict__ x, float* __restrict__ out) {
    int i = blockIdx.x * 256 + threadIdx.x;          // float4 index
    const int per_b = 512 * S / 4;
    int b = i / per_b;
    int r = i - b * per_b;
    const float4* src = (const float4*)x;
    float4* dst = (float4*)out;
    dst[(size_t)b * (768 * S / 4) + r] = src[(size_t)b * per_b + r];
}

// ---------------------------------------------------------------------------
// order-preserving compaction: qlist = {s : flag[s]==1}, klist = {s : flag[s]==0}
__global__ void compact(const int* __restrict__ flag, int* __restrict__ cnts,
                        int* __restrict__ qlist, int* __restrict__ klist) {
    __shared__ int sq[256], sk[256];
    int t = threadIdx.x;
    int base = t * 16;
    int f[16];
    int nq = 0, nk = 0;
    #pragma unroll
    for (int i = 0; i < 16; ++i) {
        f[i] = flag[base + i];
        nq += (f[i] == 1);
        nk += (f[i] == 0);
    }
    sq[t] = nq; sk[t] = nk;
    __syncthreads();
    for (int off = 1; off < 256; off <<= 1) {
        int vq = sq[t], vk = sk[t];
        int aq = (t >= off) ? sq[t - off] : 0;
        int ak = (t >= off) ? sk[t - off] : 0;
        __syncthreads();
        sq[t] = vq + aq; sk[t] = vk + ak;
        __syncthreads();
    }
    int pq = sq[t] - nq;
    int pk = sk[t] - nk;
    #pragma unroll
    for (int i = 0; i < 16; ++i) {
        if (f[i] == 1)      qlist[pq++] = base + i;
        else                klist[pk++] = base + i;
    }
    if (t == 255) { cnts[0] = sq[255]; cnts[1] = sk[255]; }
}

// ---------------------------------------------------------------------------
// invn[b][k] = 1 / max(||l[b,k,:]||, 1e-12)   (float4 over k)
__global__ void invnorm_k(const float* __restrict__ x, float* __restrict__ invn) {
    int k4 = blockIdx.x * 256 + threadIdx.x;    // float4 index over k
    int b  = blockIdx.y;
    const float4* base = (const float4*)(x + ((size_t)b * 512 + 256) * S) + k4;
    float4 acc = { 0.f, 0.f, 0.f, 0.f };
    #pragma unroll 8
    for (int c = 0; c < CH; ++c) {
        float4 v = base[(size_t)c * (S / 4)];
        acc.x += v.x * v.x; acc.y += v.y * v.y;
        acc.z += v.z * v.z; acc.w += v.w * v.w;
    }
    float4 r;
    r.x = 1.0f / fmaxf(sqrtf(acc.x), 1e-12f);
    r.y = 1.0f / fmaxf(sqrtf(acc.y), 1e-12f);
    r.z = 1.0f / fmaxf(sqrtf(acc.z), 1e-12f);
    r.w = 1.0f / fmaxf(sqrtf(acc.w), 1e-12f);
    ((float4*)(invn + ((size_t)b << 12)))[k4] = r;
}

// ---------------------------------------------------------------------------
// pack normalized active-k columns of latter into dense [c][j], j = compact k,
// in the out[:,512:768] slab (scratch until scatter_k overwrites it).
__global__ void pack_ln(const float* __restrict__ x, const int* __restrict__ cnts,
                        const int* __restrict__ klist, const float* __restrict__ invn,
                        float* __restrict__ out) {
    int j = blockIdx.x * 256 + threadIdx.x;
    int b = blockIdx.z;
    int Ak = cnts[1];
    int kk = -1; float w = 0.f;
    if (j < Ak) { kk = klist[j]; w = invn[((size_t)b << 12) + kk]; }
    const float* Lm = x + ((size_t)b * 512 + 256) * S;
    float* dst = out + ((size_t)b * 768 + 512) * S;
    #pragma unroll
    for (int c8 = 0; c8 < 8; ++c8) {
        int c = blockIdx.y * 8 + c8;
        dst[(size_t)c * S + j] = (kk >= 0) ? Lm[(size_t)c * S + kk] * w : 0.f;
    }
}

// ---------------------------------------------------------------------------
// pack active-q columns of former into dense [c][i], i = compact q,
// in the out[:,0:256] slab (scratch until copy_fl overwrites it).
__global__ void pack_f(const float* __restrict__ x, const int* __restrict__ cnts,
                       const int* __restrict__ qlist, float* __restrict__ out) {
    int i = blockIdx.x * 256 + threadIdx.x;
    int b = blockIdx.z;
    int Aq = cnts[0];
    int qq = (i < Aq) ? qlist[i] : -1;
    const float* Fm = x + (size_t)b * 512 * S;
    float* dst = out + (size_t)b * 768 * S;
    #pragma unroll
    for (int c8 = 0; c8 < 8; ++c8) {
        int c = blockIdx.y * 8 + c8;
        dst[(size_t)c * S + i] = (qq >= 0) ? Fm[(size_t)c * S + qq] : 0.f;
    }
}

// ---------------------------------------------------------------------------
// dense argmax GEMM, double-buffered 2-phase pipeline:
// per c-chunk: issue global loads for chunk t+1 -> regs, compute chunk t from
// LDS buf[cur], barrier, ds_write regs -> buf[cur^1], barrier.
__launch_bounds__(256, 4)
__global__ void argmax_gemm(const float* __restrict__ packed,  // == out
                            const int*  __restrict__ cnts,
                            const int*  __restrict__ klist,
                            float* __restrict__ pmax,
                            int*   __restrict__ pidx) {
    __shared__ float Fs[2][CK][BM];     // 2 x 8 KB
    __shared__ float Ls[2][CK][BN];     // 2 x 8 KB

    const int Aq    = cnts[0];
    const int Ak    = cnts[1];
    const int b     = blockIdx.y;
    const int split = blockIdx.x & (KSPLIT - 1);
    const int q0    = (blockIdx.x >> 3) * BM;
    if (q0 >= Aq) return;

    const int tid = threadIdx.x;
    const int tx  = tid & 15;       // k-cols: tx*4..+3 and 64+tx*4..+3
    const int ty  = tid >> 4;       // q-rows: ty*4..+3 and 64+ty*4..+3

    // staging slots: thread owns float4 slots (cc0,xx) and (cc0+8,xx) per panel
    const int cc0 = tid >> 5;             // 0..7
    const int xx  = (tid & 31) << 2;      // 0..124

    const float* Fp  = packed + (size_t)b * 768 * S;            // [c][i]
    const float* Lnb = packed + ((size_t)b * 768 + 512) * S;    // [c][j]

    const int nkt = (Ak + BN - 1) / BN;
    const int kt0 = (nkt * split) / KSPLIT;
    const int kt1 = (nkt * (split + 1)) / KSPLIT;

    float rm[8]; int ri[8];
    #pragma unroll
    for (int i = 0; i < 8; ++i) { rm[i] = NEG_INF; ri[i] = 0; }

    for (int kt = kt0; kt < kt1; ++kt) {
        const int kbase = kt * BN;

        // ---- prologue: stage chunk 0 into buf 0
        float4 rF0 = *(const float4*)&Fp [(size_t)cc0       * S + q0    + xx];
        float4 rF1 = *(const float4*)&Fp [(size_t)(cc0 + 8) * S + q0    + xx];
        float4 rL0 = *(const float4*)&Lnb[(size_t)cc0       * S + kbase + xx];
        float4 rL1 = *(const float4*)&Lnb[(size_t)(cc0 + 8) * S + kbase + xx];
        *(float4*)&Fs[0][cc0    ][xx] = rF0;
        *(float4*)&Fs[0][cc0 + 8][xx] = rF1;
        *(float4*)&Ls[0][cc0    ][xx] = rL0;
        *(float4*)&Ls[0][cc0 + 8][xx] = rL1;
        __syncthreads();

        float acc[8][8];
        #pragma unroll
        for (int a = 0; a < 8; ++a)
            #pragma unroll
            for (int c = 0; c < 8; ++c) acc[a][c] = 0.f;

        int cur = 0;
        for (int c0 = CK; c0 <= CH; c0 += CK) {
            // issue next chunk's global loads (latency hides under compute)
            if (c0 < CH) {
                rF0 = *(const float4*)&Fp [(size_t)(c0 + cc0)     * S + q0    + xx];
                rF1 = *(const float4*)&Fp [(size_t)(c0 + cc0 + 8) * S + q0    + xx];
                rL0 = *(const float4*)&Lnb[(size_t)(c0 + cc0)     * S + kbase + xx];
                rL1 = *(const float4*)&Lnb[(size_t)(c0 + cc0 + 8) * S + kbase + xx];
            }

            // compute on buf[cur]
            #pragma unroll
            for (int cc = 0; cc < CK; ++cc) {
                const float4 a0 = *(const float4*)&Fs[cur][cc][ty * 4];
                const float4 a1 = *(const float4*)&Fs[cur][cc][64 + ty * 4];
                const float4 b0 = *(const float4*)&Ls[cur][cc][tx * 4];
                const float4 b1 = *(const float4*)&Ls[cur][cc][64 + tx * 4];
                float av[8] = { a0.x, a0.y, a0.z, a0.w, a1.x, a1.y, a1.z, a1.w };
                float bv[8] = { b0.x, b0.y, b0.z, b0.w, b1.x, b1.y, b1.z, b1.w };
                #pragma unroll
                for (int qq = 0; qq < 8; ++qq)
                    #pragma unroll
                    for (int jj = 0; jj < 8; ++jj)
                        acc[qq][jj] += av[qq] * bv[jj];
            }
            __syncthreads();          // everyone done reading buf[cur]

            if (c0 < CH) {
                *(float4*)&Fs[cur ^ 1][cc0    ][xx] = rF0;
                *(float4*)&Fs[cur ^ 1][cc0 + 8][xx] = rF1;
                *(float4*)&Ls[cur ^ 1][cc0    ][xx] = rL0;
                *(float4*)&Ls[cur ^ 1][cc0 + 8][xx] = rL1;
                __syncthreads();      // buf[cur^1] ready for next iteration
            }
            cur ^= 1;
        }

        // fold k-tile into running (max, idx); ascending-k within thread
        #pragma unroll
        for (int jj = 0; jj < 8; ++jj) {
            int col = (jj < 4) ? (tx * 4 + jj) : (64 + tx * 4 + (jj - 4));
            int kp  = kbase + col;
            if (kp < Ak) {
                int kk = klist[kp];
                #pragma unroll
                for (int qq = 0; qq < 8; ++qq) {
                    float sv = acc[qq][jj];
                    if (sv > rm[qq]) { rm[qq] = sv; ri[qq] = kk; }
                    else if (sv == rm[qq] && kk < ri[qq]) { ri[qq] = kk; }
                }
            }
        }
    }

    // reduce across the 16 lanes sharing each q-row group
    #pragma unroll
    for (int qq = 0; qq < 8; ++qq) {
        float m = rm[qq]; int id = ri[qq];
        #pragma unroll
        for (int off = 8; off; off >>= 1) {
            float om = __shfl_xor(m, off, 64);
            int   oi = __shfl_xor(id, off, 64);
            if (om > m || (om == m && oi < id)) { m = om; id = oi; }
        }
        if (tx == 0) {
            int row = (qq < 4) ? (ty * 4 + qq) : (64 + ty * 4 + (qq - 4));
            int qp  = q0 + row;
            if (qp < Aq) {
                size_t o = ((size_t)((b << 12) + qp)) * KSPLIT + split;
                pmax[o] = m;
                pidx[o] = id;
            }
        }
    }
}

// ---------------------------------------------------------------------------
// combine k-split partials -> idxb[b][q]  (strict > keeps lowest split)
__global__ void combine(const int* __restrict__ cnts, const int* __restrict__ qlist,
                        const float* __restrict__ pmax, const int* __restrict__ pidx,
                        int* __restrict__ idxb) {
    int qp = blockIdx.x * 256 + threadIdx.x;
    int b  = blockIdx.y;
    if (qp >= cnts[0]) return;
    size_t base = (size_t)((b << 12) + qp) * KSPLIT;
    float m = pmax[base]; int id = pidx[base];
    #pragma unroll
    for (int s = 1; s < KSPLIT; ++s) {
        float om = pmax[base + s]; int oi = pidx[base + s];
        if (om > m) { m = om; id = oi; }
    }
    idxb[((size_t)b << 12) + qlist[qp]] = id;
}

// ---------------------------------------------------------------------------
// out[b][512+c][q] = flag[q]==1 ? latter[b][c][idx[b][q]] : 0
__global__ void scatter_k(const float* __restrict__ x, const int* __restrict__ flag,
                          const int* __restrict__ idxb, float* __restrict__ out) {
    int e = blockIdx.x * 256 + threadIdx.x;
    int q = e & (S - 1);
    int c = (e >> 12) & 255;
    int b = e >> 20;
    float v = 0.f;
    if (flag[q] == 1) {
        int id = idxb[((size_t)b << 12) + q];
        v = x[((size_t)b * 512 + 256 + c) * S + id];
    }
    out[((size_t)b * 768 + 512 + c) * S + q] = v;
}

// ---------------------------------------------------------------------------
extern "C" void kernel_launch(void* const* d_in, const int* in_sizes, int n_in,
                              void* d_out, int out_size, void* d_ws, size_t ws_size,
                              hipStream_t stream) {
    const float* x    = (const float*)d_in[0];
    const int*   flag = (const int*)d_in[2];
    float*       out  = (float*)d_out;

    char* ws = (char*)d_ws;
    int*   cnts  = (int*)(ws);                 // 2 ints
    int*   qlist = (int*)(ws + 1024);          // 16 KB
    int*   klist = (int*)(ws + 17408);         // 16 KB
    float* invn  = (float*)(ws + 33792);       // 128 KB
    int*   idxb  = (int*)(ws + 164864);        // 128 KB
    float* pmax  = (float*)(ws + 295936);      // 1 MB  (8*4096*8)
    int*   pidx  = (int*)(ws + 1344512);       // 1 MB

    hipLaunchKernelGGL(compact,     dim3(1),                        dim3(256), 0, stream, flag, cnts, qlist, klist);
    hipLaunchKernelGGL(invnorm_k,   dim3(S / 4 / 256, NB),          dim3(256), 0, stream, x, invn);
    hipLaunchKernelGGL(pack_ln,     dim3(S / 256, CH / 8, NB),      dim3(256), 0, stream, x, cnts, klist, invn, out);
    hipLaunchKernelGGL(pack_f,      dim3(S / 256, CH / 8, NB),      dim3(256), 0, stream, x, cnts, qlist, out);
    hipLaunchKernelGGL(argmax_gemm, dim3((S / BM) * KSPLIT, NB),    dim3(256), 0, stream,
                       out, cnts, klist, pmax, pidx);
    hipLaunchKernelGGL(combine,     dim3(S / 256, NB),              dim3(256), 0, stream, cnts, qlist, pmax, pidx, idxb);
    hipLaunchKernelGGL(copy_fl,     dim3((NB * 512 * S / 4) / 256), dim3(256), 0, stream, x, out);
    hipLaunchKernelGGL(scatter_k,   dim3((NB * CH * S) / 256),      dim3(256), 0, stream, x, flag, idxb, out);
}

// Round 6
// 358.862 us; speedup vs baseline: 12.4790x; 12.4790x over previous
//
#include <hip/hip_runtime.h>

#define S    4096
#define CH   256
#define NB   8

#define BM   64
#define BN   128
#define CK   32
#define NCPK (CH / CK)          // 8 c-chunks per k-tile
#define KSPLIT 8

#define NEG_INF (-3.402823466e38f)

// ---------------------------------------------------------------------------
// out[:, 0:512] = input  (runs AFTER argmax_gemm — that slab is GEMM scratch)
__global__ void copy_fl(const float* __restrict__ x, float* __restrict__ out) {
    int i = blockIdx.x * 256 + threadIdx.x;          // float4 index
    const int per_b = 512 * S / 4;
    int b = i / per_b;
    int r = i - b * per_b;
    const float4* src = (const float4*)x;
    float4* dst = (float4*)out;
    dst[(size_t)b * (768 * S / 4) + r] = src[(size_t)b * per_b + r];
}

// ---------------------------------------------------------------------------
// order-preserving compaction: qlist = {s : flag[s]==1}, klist = {s : flag[s]==0}
__global__ void compact(const int* __restrict__ flag, int* __restrict__ cnts,
                        int* __restrict__ qlist, int* __restrict__ klist) {
    __shared__ int sq[256], sk[256];
    int t = threadIdx.x;
    int base = t * 16;
    int f[16];
    int nq = 0, nk = 0;
    #pragma unroll
    for (int i = 0; i < 16; ++i) {
        f[i] = flag[base + i];
        nq += (f[i] == 1);
        nk += (f[i] == 0);
    }
    sq[t] = nq; sk[t] = nk;
    __syncthreads();
    for (int off = 1; off < 256; off <<= 1) {
        int vq = sq[t], vk = sk[t];
        int aq = (t >= off) ? sq[t - off] : 0;
        int ak = (t >= off) ? sk[t - off] : 0;
        __syncthreads();
        sq[t] = vq + aq; sk[t] = vk + ak;
        __syncthreads();
    }
    int pq = sq[t] - nq;
    int pk = sk[t] - nk;
    #pragma unroll
    for (int i = 0; i < 16; ++i) {
        if (f[i] == 1)      qlist[pq++] = base + i;
        else                klist[pk++] = base + i;
    }
    if (t == 255) { cnts[0] = sq[255]; cnts[1] = sk[255]; }
}

// ---------------------------------------------------------------------------
// invn[b][k] = 1 / max(||l[b,k,:]||, 1e-12)   (float4 over k)
__global__ void invnorm_k(const float* __restrict__ x, float* __restrict__ invn) {
    int k4 = blockIdx.x * 256 + threadIdx.x;    // float4 index over k
    int b  = blockIdx.y;
    const float4* base = (const float4*)(x + ((size_t)b * 512 + 256) * S) + k4;
    float4 acc = { 0.f, 0.f, 0.f, 0.f };
    #pragma unroll 8
    for (int c = 0; c < CH; ++c) {
        float4 v = base[(size_t)c * (S / 4)];
        acc.x += v.x * v.x; acc.y += v.y * v.y;
        acc.z += v.z * v.z; acc.w += v.w * v.w;
    }
    float4 r;
    r.x = 1.0f / fmaxf(sqrtf(acc.x), 1e-12f);
    r.y = 1.0f / fmaxf(sqrtf(acc.y), 1e-12f);
    r.z = 1.0f / fmaxf(sqrtf(acc.z), 1e-12f);
    r.w = 1.0f / fmaxf(sqrtf(acc.w), 1e-12f);
    ((float4*)(invn + ((size_t)b << 12)))[k4] = r;
}

// ---------------------------------------------------------------------------
// pack normalized active-k columns of latter into dense [c][j], j = compact k,
// in the out[:,512:768] slab (scratch until scatter_k overwrites it).
__global__ void pack_ln(const float* __restrict__ x, const int* __restrict__ cnts,
                        const int* __restrict__ klist, const float* __restrict__ invn,
                        float* __restrict__ out) {
    int j = blockIdx.x * 256 + threadIdx.x;
    int b = blockIdx.z;
    int Ak = cnts[1];
    int kk = -1; float w = 0.f;
    if (j < Ak) { kk = klist[j]; w = invn[((size_t)b << 12) + kk]; }
    const float* Lm = x + ((size_t)b * 512 + 256) * S;
    float* dst = out + ((size_t)b * 768 + 512) * S;
    #pragma unroll
    for (int c8 = 0; c8 < 8; ++c8) {
        int c = blockIdx.y * 8 + c8;
        dst[(size_t)c * S + j] = (kk >= 0) ? Lm[(size_t)c * S + kk] * w : 0.f;
    }
}

// ---------------------------------------------------------------------------
// pack active-q columns of former into dense [c][i], i = compact q,
// in the out[:,0:256] slab (scratch until copy_fl overwrites it).
__global__ void pack_f(const float* __restrict__ x, const int* __restrict__ cnts,
                       const int* __restrict__ qlist, float* __restrict__ out) {
    int i = blockIdx.x * 256 + threadIdx.x;
    int b = blockIdx.z;
    int Aq = cnts[0];
    int qq = (i < Aq) ? qlist[i] : -1;
    const float* Fm = x + (size_t)b * 512 * S;
    float* dst = out + (size_t)b * 768 * S;
    #pragma unroll
    for (int c8 = 0; c8 < 8; ++c8) {
        int c = blockIdx.y * 8 + c8;
        dst[(size_t)c * S + i] = (qq >= 0) ? Fm[(size_t)c * S + qq] : 0.f;
    }
}

// ---------------------------------------------------------------------------
// dense argmax GEMM: BM=64 x BN=128, CK=32, 4q x 8k per thread, flattened
// chunk loop with register-prefetch double-buffered LDS. No VGPR cap.
__launch_bounds__(256)
__global__ void argmax_gemm(const float* __restrict__ packed,  // == out
                            const int*  __restrict__ cnts,
                            const int*  __restrict__ klist,
                            float* __restrict__ pmax,
                            int*   __restrict__ pidx) {
    __shared__ float Fs[2][CK][BM];     // 2 x 8 KB
    __shared__ float Ls[2][CK][BN];     // 2 x 16 KB

    const int Aq    = cnts[0];
    const int Ak    = cnts[1];
    const int b     = blockIdx.y;
    const int split = blockIdx.x & (KSPLIT - 1);
    const int q0    = (blockIdx.x >> 3) * BM;
    if (q0 >= Aq) return;

    const int tid = threadIdx.x;
    const int tx  = tid & 15;       // k-cols: tx*4..+3 and 64+tx*4..+3
    const int ty  = tid >> 4;       // q-rows: ty*4..ty*4+3  (ty 0..15)

    // staging slots (float4): F -> (ccF, xF) and (ccF+16, xF); L -> ccL+{0,8,16,24}, xL
    const int ccF = tid >> 4;             // 0..15
    const int xF  = (tid & 15) << 2;      // 0..60
    const int ccL = tid >> 5;             // 0..7
    const int xL  = (tid & 31) << 2;      // 0..124

    const float* Fp  = packed + (size_t)b * 768 * S;            // [c][i]
    const float* Lnb = packed + ((size_t)b * 768 + 512) * S;    // [c][j]

    const int nkt = (Ak + BN - 1) / BN;
    const int kt0 = (nkt * split) / KSPLIT;
    const int kt1 = (nkt * (split + 1)) / KSPLIT;
    const int nchunk = (kt1 - kt0) * NCPK;

    float rm[4]; int ri[4];
    #pragma unroll
    for (int i = 0; i < 4; ++i) { rm[i] = NEG_INF; ri[i] = 0; }

    if (nchunk > 0) {
        // ---- prologue: stage chunk 0 into buf 0
        {
            const int kbase = kt0 * BN;
            float4 rF0 = *(const float4*)&Fp [(size_t)ccF        * S + q0    + xF];
            float4 rF1 = *(const float4*)&Fp [(size_t)(ccF + 16) * S + q0    + xF];
            float4 rL0 = *(const float4*)&Lnb[(size_t)ccL        * S + kbase + xL];
            float4 rL1 = *(const float4*)&Lnb[(size_t)(ccL + 8)  * S + kbase + xL];
            float4 rL2 = *(const float4*)&Lnb[(size_t)(ccL + 16) * S + kbase + xL];
            float4 rL3 = *(const float4*)&Lnb[(size_t)(ccL + 24) * S + kbase + xL];
            *(float4*)&Fs[0][ccF     ][xF] = rF0;
            *(float4*)&Fs[0][ccF + 16][xF] = rF1;
            *(float4*)&Ls[0][ccL     ][xL] = rL0;
            *(float4*)&Ls[0][ccL + 8 ][xL] = rL1;
            *(float4*)&Ls[0][ccL + 16][xL] = rL2;
            *(float4*)&Ls[0][ccL + 24][xL] = rL3;
        }
        __syncthreads();

        float acc[4][8];
        #pragma unroll
        for (int a = 0; a < 4; ++a)
            #pragma unroll
            for (int c = 0; c < 8; ++c) acc[a][c] = 0.f;

        float4 rF0, rF1, rL0, rL1, rL2, rL3;

        for (int t = 0; t < nchunk; ++t) {
            const int cur = t & 1;
            const int kbase_cur = (kt0 + (t >> 3)) * BN;

            // issue next chunk's global loads (hide under compute below)
            if (t + 1 < nchunk) {
                const int tn    = t + 1;
                const int c0n   = (tn & 7) * CK;
                const int kbn   = (kt0 + (tn >> 3)) * BN;
                rF0 = *(const float4*)&Fp [(size_t)(c0n + ccF)      * S + q0  + xF];
                rF1 = *(const float4*)&Fp [(size_t)(c0n + ccF + 16) * S + q0  + xF];
                rL0 = *(const float4*)&Lnb[(size_t)(c0n + ccL)      * S + kbn + xL];
                rL1 = *(const float4*)&Lnb[(size_t)(c0n + ccL + 8)  * S + kbn + xL];
                rL2 = *(const float4*)&Lnb[(size_t)(c0n + ccL + 16) * S + kbn + xL];
                rL3 = *(const float4*)&Lnb[(size_t)(c0n + ccL + 24) * S + kbn + xL];
            }

            // compute on buf[cur]
            #pragma unroll
            for (int cc = 0; cc < CK; ++cc) {
                const float4 a0 = *(const float4*)&Fs[cur][cc][ty * 4];
                const float4 b0 = *(const float4*)&Ls[cur][cc][tx * 4];
                const float4 b1 = *(const float4*)&Ls[cur][cc][64 + tx * 4];
                float av[4] = { a0.x, a0.y, a0.z, a0.w };
                float bv[8] = { b0.x, b0.y, b0.z, b0.w, b1.x, b1.y, b1.z, b1.w };
                #pragma unroll
                for (int qq = 0; qq < 4; ++qq)
                    #pragma unroll
                    for (int jj = 0; jj < 8; ++jj)
                        acc[qq][jj] += av[qq] * bv[jj];
            }

            // last c-chunk of this k-tile: fold acc into running (max, idx)
            if ((t & 7) == 7) {
                #pragma unroll
                for (int jj = 0; jj < 8; ++jj) {
                    int col = (jj < 4) ? (tx * 4 + jj) : (64 + tx * 4 + (jj - 4));
                    int kp  = kbase_cur + col;
                    if (kp < Ak) {
                        int kk = klist[kp];
                        #pragma unroll
                        for (int qq = 0; qq < 4; ++qq) {
                            float sv = acc[qq][jj];
                            if (sv > rm[qq]) { rm[qq] = sv; ri[qq] = kk; }
                            else if (sv == rm[qq] && kk < ri[qq]) { ri[qq] = kk; }
                        }
                    }
                }
                #pragma unroll
                for (int a = 0; a < 4; ++a)
                    #pragma unroll
                    for (int c = 0; c < 8; ++c) acc[a][c] = 0.f;
            }

            __syncthreads();          // everyone done reading buf[cur]
            if (t + 1 < nchunk) {
                *(float4*)&Fs[cur ^ 1][ccF     ][xF] = rF0;
                *(float4*)&Fs[cur ^ 1][ccF + 16][xF] = rF1;
                *(float4*)&Ls[cur ^ 1][ccL     ][xL] = rL0;
                *(float4*)&Ls[cur ^ 1][ccL + 8 ][xL] = rL1;
                *(float4*)&Ls[cur ^ 1][ccL + 16][xL] = rL2;
                *(float4*)&Ls[cur ^ 1][ccL + 24][xL] = rL3;
                __syncthreads();      // buf[cur^1] ready for next iteration
            }
        }
    }

    // reduce across the 16 lanes sharing each q-row group
    #pragma unroll
    for (int qq = 0; qq < 4; ++qq) {
        float m = rm[qq]; int id = ri[qq];
        #pragma unroll
        for (int off = 8; off; off >>= 1) {
            float om = __shfl_xor(m, off, 64);
            int   oi = __shfl_xor(id, off, 64);
            if (om > m || (om == m && oi < id)) { m = om; id = oi; }
        }
        if (tx == 0) {
            int qp = q0 + ty * 4 + qq;
            if (qp < Aq) {
                size_t o = ((size_t)((b << 12) + qp)) * KSPLIT + split;
                pmax[o] = m;
                pidx[o] = id;
            }
        }
    }
}

// ---------------------------------------------------------------------------
// combine k-split partials -> idxb[b][q]  (strict > keeps lowest split)
__global__ void combine(const int* __restrict__ cnts, const int* __restrict__ qlist,
                        const float* __restrict__ pmax, const int* __restrict__ pidx,
                        int* __restrict__ idxb) {
    int qp = blockIdx.x * 256 + threadIdx.x;
    int b  = blockIdx.y;
    if (qp >= cnts[0]) return;
    size_t base = (size_t)((b << 12) + qp) * KSPLIT;
    float m = pmax[base]; int id = pidx[base];
    #pragma unroll
    for (int s = 1; s < KSPLIT; ++s) {
        float om = pmax[base + s]; int oi = pidx[base + s];
        if (om > m) { m = om; id = oi; }
    }
    idxb[((size_t)b << 12) + qlist[qp]] = id;
}

// ---------------------------------------------------------------------------
// out[b][512+c][q] = flag[q]==1 ? latter[b][c][idx[b][q]] : 0
__global__ void scatter_k(const float* __restrict__ x, const int* __restrict__ flag,
                          const int* __restrict__ idxb, float* __restrict__ out) {
    int e = blockIdx.x * 256 + threadIdx.x;
    int q = e & (S - 1);
    int c = (e >> 12) & 255;
    int b = e >> 20;
    float v = 0.f;
    if (flag[q] == 1) {
        int id = idxb[((size_t)b << 12) + q];
        v = x[((size_t)b * 512 + 256 + c) * S + id];
    }
    out[((size_t)b * 768 + 512 + c) * S + q] = v;
}

// ---------------------------------------------------------------------------
extern "C" void kernel_launch(void* const* d_in, const int* in_sizes, int n_in,
                              void* d_out, int out_size, void* d_ws, size_t ws_size,
                              hipStream_t stream) {
    const float* x    = (const float*)d_in[0];
    const int*   flag = (const int*)d_in[2];
    float*       out  = (float*)d_out;

    char* ws = (char*)d_ws;
    int*   cnts  = (int*)(ws);                 // 2 ints
    int*   qlist = (int*)(ws + 1024);          // 16 KB
    int*   klist = (int*)(ws + 17408);         // 16 KB
    float* invn  = (float*)(ws + 33792);       // 128 KB
    int*   idxb  = (int*)(ws + 164864);        // 128 KB
    float* pmax  = (float*)(ws + 295936);      // 1 MB  (8*4096*8)
    int*   pidx  = (int*)(ws + 1344512);       // 1 MB

    hipLaunchKernelGGL(compact,     dim3(1),                        dim3(256), 0, stream, flag, cnts, qlist, klist);
    hipLaunchKernelGGL(invnorm_k,   dim3(S / 4 / 256, NB),          dim3(256), 0, stream, x, invn);
    hipLaunchKernelGGL(pack_ln,     dim3(S / 256, CH / 8, NB),      dim3(256), 0, stream, x, cnts, klist, invn, out);
    hipLaunchKernelGGL(pack_f,      dim3(S / 256, CH / 8, NB),      dim3(256), 0, stream, x, cnts, qlist, out);
    hipLaunchKernelGGL(argmax_gemm, dim3((S / BM) * KSPLIT, NB),    dim3(256), 0, stream,
                       out, cnts, klist, pmax, pidx);
    hipLaunchKernelGGL(combine,     dim3(S / 256, NB),              dim3(256), 0, stream, cnts, qlist, pmax, pidx, idxb);
    hipLaunchKernelGGL(copy_fl,     dim3((NB * 512 * S / 4) / 256), dim3(256), 0, stream, x, out);
    hipLaunchKernelGGL(scatter_k,   dim3((NB * CH * S) / 256),      dim3(256), 0, stream, x, flag, idxb, out);
}

// Round 7
// 353.634 us; speedup vs baseline: 12.6635x; 1.0148x over previous
//
#include <hip/hip_runtime.h>

#define S    4096
#define CH   256
#define NB   8

#define BM   128
#define BN   128
#define CKC  32
#define KSPLIT 8

#define SFF  256.0f     // F pre-scale (power of 2; argmax-invariant)
#define SLL  1024.0f    // L pre-scale

#define NEG_INF (-3.402823466e38f)

typedef _Float16 half8 __attribute__((ext_vector_type(8)));
typedef float    f32x4 __attribute__((ext_vector_type(4)));

// ---------------------------------------------------------------------------
// out[:, 0:512] = input  (runs AFTER argmax — that slab holds the f16 panels)
__global__ void copy_fl(const float* __restrict__ x, float* __restrict__ out) {
    int i = blockIdx.x * 256 + threadIdx.x;          // float4 index
    const int per_b = 512 * S / 4;
    int b = i / per_b;
    int r = i - b * per_b;
    const float4* src = (const float4*)x;
    float4* dst = (float4*)out;
    dst[(size_t)b * (768 * S / 4) + r] = src[(size_t)b * per_b + r];
}

// ---------------------------------------------------------------------------
__global__ void compact(const int* __restrict__ flag, int* __restrict__ cnts,
                        int* __restrict__ qlist, int* __restrict__ klist) {
    __shared__ int sq[256], sk[256];
    int t = threadIdx.x;
    int base = t * 16;
    int f[16];
    int nq = 0, nk = 0;
    #pragma unroll
    for (int i = 0; i < 16; ++i) {
        f[i] = flag[base + i];
        nq += (f[i] == 1);
        nk += (f[i] == 0);
    }
    sq[t] = nq; sk[t] = nk;
    __syncthreads();
    for (int off = 1; off < 256; off <<= 1) {
        int vq = sq[t], vk = sk[t];
        int aq = (t >= off) ? sq[t - off] : 0;
        int ak = (t >= off) ? sk[t - off] : 0;
        __syncthreads();
        sq[t] = vq + aq; sk[t] = vk + ak;
        __syncthreads();
    }
    int pq = sq[t] - nq;
    int pk = sk[t] - nk;
    #pragma unroll
    for (int i = 0; i < 16; ++i) {
        if (f[i] == 1)      qlist[pq++] = base + i;
        else                klist[pk++] = base + i;
    }
    if (t == 255) { cnts[0] = sq[255]; cnts[1] = sk[255]; }
}

// ---------------------------------------------------------------------------
__global__ void invnorm_k(const float* __restrict__ x, float* __restrict__ invn) {
    int k4 = blockIdx.x * 256 + threadIdx.x;
    int b  = blockIdx.y;
    const float4* base = (const float4*)(x + ((size_t)b * 512 + 256) * S) + k4;
    float4 acc = { 0.f, 0.f, 0.f, 0.f };
    #pragma unroll 8
    for (int c = 0; c < CH; ++c) {
        float4 v = base[(size_t)c * (S / 4)];
        acc.x += v.x * v.x; acc.y += v.y * v.y;
        acc.z += v.z * v.z; acc.w += v.w * v.w;
    }
    float4 r;
    r.x = 1.0f / fmaxf(sqrtf(acc.x), 1e-12f);
    r.y = 1.0f / fmaxf(sqrtf(acc.y), 1e-12f);
    r.z = 1.0f / fmaxf(sqrtf(acc.z), 1e-12f);
    r.w = 1.0f / fmaxf(sqrtf(acc.w), 1e-12f);
    ((float4*)(invn + ((size_t)b << 12)))[k4] = r;
}

// ---------------------------------------------------------------------------
// f16 hi/lo panels, row-major [row][c], in the out[:,0:512] slab per batch:
//   FH | FL | LH | LL, each S*CH f16 (2 MB), total 8 MB = the 512-ch slab.
// pack_f16: row r (compact q), FH/FL = split(F[c][qlist[r]] * 256)
__global__ void pack_f16(const float* __restrict__ x, const int* __restrict__ cnts,
                         const int* __restrict__ qlist, float* __restrict__ out) {
    const int b = blockIdx.y;
    const int A = cnts[0];
    const int bound = (A + BM - 1) & ~(BM - 1);
    const int r = blockIdx.x * 32 + (threadIdx.x >> 3);
    if (r >= bound) return;
    const int cseg = (threadIdx.x & 7) * 32;
    _Float16* pb = (_Float16*)(out + (size_t)b * 768 * S);
    _Float16* FH = pb;
    _Float16* FL = pb + (size_t)S * CH;
    const float* src = x + (size_t)b * 512 * S;
    const int qq = (r < A) ? qlist[r] : -1;
    #pragma unroll
    for (int g = 0; g < 4; ++g) {
        union { _Float16 u[8]; float4 v; } hb, lb;
        #pragma unroll
        for (int j = 0; j < 8; ++j) {
            float v = 0.f;
            if (qq >= 0) v = src[(size_t)(cseg + g * 8 + j) * S + qq] * SFF;
            _Float16 h = (_Float16)v;
            float res = v - (float)h;
            hb.u[j] = h;
            lb.u[j] = (_Float16)res;
        }
        *(float4*)&FH[(size_t)r * CH + cseg + g * 8] = hb.v;
        *(float4*)&FL[(size_t)r * CH + cseg + g * 8] = lb.v;
    }
}

// pack_l16: row j (compact k), LH/LL = split(L[c][klist[j]] * invn * 1024)
__global__ void pack_l16(const float* __restrict__ x, const int* __restrict__ cnts,
                         const int* __restrict__ klist, const float* __restrict__ invn,
                         float* __restrict__ out) {
    const int b = blockIdx.y;
    const int A = cnts[1];
    const int bound = (A + BN - 1) & ~(BN - 1);
    const int r = blockIdx.x * 32 + (threadIdx.x >> 3);
    if (r >= bound) return;
    const int cseg = (threadIdx.x & 7) * 32;
    _Float16* pb = (_Float16*)(out + (size_t)b * 768 * S);
    _Float16* LH = pb + 2 * (size_t)S * CH;
    _Float16* LL = pb + 3 * (size_t)S * CH;
    const float* src = x + ((size_t)b * 512 + 256) * S;
    int kk = -1; float w = 0.f;
    if (r < A) { kk = klist[r]; w = invn[((size_t)b << 12) + kk] * SLL; }
    #pragma unroll
    for (int g = 0; g < 4; ++g) {
        union { _Float16 u[8]; float4 v; } hb, lb;
        #pragma unroll
        for (int j = 0; j < 8; ++j) {
            float v = 0.f;
            if (kk >= 0) v = src[(size_t)(cseg + g * 8 + j) * S + kk] * w;
            _Float16 h = (_Float16)v;
            float res = v - (float)h;
            hb.u[j] = h;
            lb.u[j] = (_Float16)res;
        }
        *(float4*)&LH[(size_t)r * CH + cseg + g * 8] = hb.v;
        *(float4*)&LL[(size_t)r * CH + cseg + g * 8] = lb.v;
    }
}

// ---------------------------------------------------------------------------
// MFMA argmax GEMM: sim = Fh.Lh + Fh.Ll + Fl.Lh (fp32 accum, exact argmax).
// Block 128q x 128k, 4 waves (each 32q x 128k), CK=32 per chunk.
// LDS rows 128 B = [h 64B | l 64B], XOR-swizzled byte ^= (row&7)<<4.
__launch_bounds__(256)
__global__ void argmax_mfma(const float* __restrict__ outbuf,
                            const int*  __restrict__ cnts,
                            const int*  __restrict__ klist,
                            float* __restrict__ pmax,
                            int*   __restrict__ pidx) {
    __shared__ char ldsF[BM * 128];    // 16 KB
    __shared__ char ldsL[BN * 128];    // 16 KB

    const int Aq    = cnts[0];
    const int Ak    = cnts[1];
    const int b     = blockIdx.y;
    const int split = blockIdx.x & (KSPLIT - 1);
    const int q0    = (blockIdx.x >> 3) * BM;
    if (q0 >= Aq) return;

    const int tid  = threadIdx.x;
    const int lane = tid & 63;
    const int wid  = tid >> 6;      // wave: q rows wid*32..+31
    const int l15  = lane & 15;
    const int l4   = lane >> 4;

    const _Float16* pb  = (const _Float16*)(outbuf + (size_t)b * 768 * S);
    const _Float16* FHg = pb;
    const _Float16* FLg = pb + (size_t)S * CH;
    const _Float16* LHg = pb + 2 * (size_t)S * CH;
    const _Float16* LLg = pb + 3 * (size_t)S * CH;

    const int nkt = (Ak + BN - 1) / BN;
    const int kt0 = (nkt * split) / KSPLIT;
    const int kt1 = (nkt * (split + 1)) / KSPLIT;

    float rm[8]; int ri[8];
    #pragma unroll
    for (int i = 0; i < 8; ++i) { rm[i] = NEG_INF; ri[i] = 0; }

    // staging slots: thread owns (row=srow+32p, seg=sseg) 16B chunks, p=0..3
    const int srow   = tid >> 3;
    const int sseg   = tid & 7;
    const int swhich = sseg >> 2;        // 0=hi, 1=lo
    const int scs8   = (sseg & 3) * 8;   // c offset within chunk
    const int sswz   = (srow & 7) << 4;  // row&7 invariant across p (+32)
    const _Float16* Fsrc = swhich ? FLg : FHg;
    const _Float16* Lsrc = swhich ? LLg : LHg;

    if (kt0 < kt1) {
        const int total = (kt1 - kt0) * 8;

        half8 fF[4], fL[4];
        {
            const int kb0 = kt0 * BN;
            #pragma unroll
            for (int p = 0; p < 4; ++p) {
                int row = srow + 32 * p;
                fF[p] = *(const half8*)&Fsrc[(size_t)(q0  + row) * CH + scs8];
                fL[p] = *(const half8*)&Lsrc[(size_t)(kb0 + row) * CH + scs8];
            }
        }

        f32x4 acc[2][8];
        #pragma unroll
        for (int mt = 0; mt < 2; ++mt)
            #pragma unroll
            for (int nt = 0; nt < 8; ++nt) acc[mt][nt] = (f32x4){0.f,0.f,0.f,0.f};

        for (int t = 0; t < total; ++t) {
            __syncthreads();    // previous compute done reading LDS
            #pragma unroll
            for (int p = 0; p < 4; ++p) {
                int row = srow + 32 * p;
                *(half8*)(ldsF + row * 128 + ((sseg * 16) ^ sswz)) = fF[p];
                *(half8*)(ldsL + row * 128 + ((sseg * 16) ^ sswz)) = fL[p];
            }
            if (t + 1 < total) {
                const int tn  = t + 1;
                const int c0n = (tn & 7) * CKC;
                const int kbn = (kt0 + (tn >> 3)) * BN;
                #pragma unroll
                for (int p = 0; p < 4; ++p) {
                    int row = srow + 32 * p;
                    fF[p] = *(const half8*)&Fsrc[(size_t)(q0  + row) * CH + c0n + scs8];
                    fL[p] = *(const half8*)&Lsrc[(size_t)(kbn + row) * CH + c0n + scs8];
                }
            }
            __syncthreads();    // LDS chunk ready

            half8 ah[2], al[2];
            #pragma unroll
            for (int mt = 0; mt < 2; ++mt) {
                int row = wid * 32 + mt * 16 + l15;
                int swz = (row & 7) << 4;
                const char* rb = ldsF + row * 128;
                ah[mt] = *(const half8*)(rb + (((l4 * 16)     ) ^ swz));
                al[mt] = *(const half8*)(rb + (((l4 * 16) + 64) ^ swz));
            }
            #pragma unroll
            for (int nt = 0; nt < 8; ++nt) {
                int rowb = nt * 16 + l15;
                int swzb = (rowb & 7) << 4;
                const char* rbb = ldsL + rowb * 128;
                half8 bh = *(const half8*)(rbb + (((l4 * 16)     ) ^ swzb));
                half8 bl = *(const half8*)(rbb + (((l4 * 16) + 64) ^ swzb));
                #pragma unroll
                for (int mt = 0; mt < 2; ++mt) {
                    acc[mt][nt] = __builtin_amdgcn_mfma_f32_16x16x32_f16(ah[mt], bh, acc[mt][nt], 0, 0, 0);
                    acc[mt][nt] = __builtin_amdgcn_mfma_f32_16x16x32_f16(ah[mt], bl, acc[mt][nt], 0, 0, 0);
                    acc[mt][nt] = __builtin_amdgcn_mfma_f32_16x16x32_f16(al[mt], bh, acc[mt][nt], 0, 0, 0);
                }
            }

            if ((t & 7) == 7) {     // end of k-tile: fold argmax, reset acc
                const int kb = (kt0 + (t >> 3)) * BN;
                #pragma unroll
                for (int mt = 0; mt < 2; ++mt)
                    #pragma unroll
                    for (int r = 0; r < 4; ++r) {
                        const int ix = mt * 4 + r;
                        #pragma unroll
                        for (int nt = 0; nt < 8; ++nt) {
                            int kp = kb + nt * 16 + l15;
                            if (kp < Ak) {
                                int kk = klist[kp];
                                float sv = acc[mt][nt][r];
                                if (sv > rm[ix]) { rm[ix] = sv; ri[ix] = kk; }
                                else if (sv == rm[ix] && kk < ri[ix]) { ri[ix] = kk; }
                            }
                        }
                    }
                #pragma unroll
                for (int mt = 0; mt < 2; ++mt)
                    #pragma unroll
                    for (int nt = 0; nt < 8; ++nt) acc[mt][nt] = (f32x4){0.f,0.f,0.f,0.f};
            }
        }
    }

    // reduce across the 16 lanes sharing each q-row (lanes with same l4)
    #pragma unroll
    for (int mt = 0; mt < 2; ++mt)
        #pragma unroll
        for (int r = 0; r < 4; ++r) {
            const int ix = mt * 4 + r;
            float m = rm[ix]; int id = ri[ix];
            #pragma unroll
            for (int off = 8; off; off >>= 1) {
                float om = __shfl_xor(m, off, 64);
                int   oi = __shfl_xor(id, off, 64);
                if (om > m || (om == m && oi < id)) { m = om; id = oi; }
            }
            if (l15 == 0) {
                int qp = q0 + wid * 32 + mt * 16 + l4 * 4 + r;
                if (qp < Aq) {
                    size_t o = ((size_t)((b << 12) + qp)) * KSPLIT + split;
                    pmax[o] = m;
                    pidx[o] = id;
                }
            }
        }
}

// ---------------------------------------------------------------------------
__global__ void combine(const int* __restrict__ cnts, const int* __restrict__ qlist,
                        const float* __restrict__ pmax, const int* __restrict__ pidx,
                        int* __restrict__ idxb) {
    int qp = blockIdx.x * 256 + threadIdx.x;
    int b  = blockIdx.y;
    if (qp >= cnts[0]) return;
    size_t base = (size_t)((b << 12) + qp) * KSPLIT;
    float m = pmax[base]; int id = pidx[base];
    #pragma unroll
    for (int s = 1; s < KSPLIT; ++s) {
        float om = pmax[base + s]; int oi = pidx[base + s];
        if (om > m) { m = om; id = oi; }
    }
    idxb[((size_t)b << 12) + qlist[qp]] = id;
}

// ---------------------------------------------------------------------------
__global__ void scatter_k(const float* __restrict__ x, const int* __restrict__ flag,
                          const int* __restrict__ idxb, float* __restrict__ out) {
    int e = blockIdx.x * 256 + threadIdx.x;
    int q = e & (S - 1);
    int c = (e >> 12) & 255;
    int b = e >> 20;
    float v = 0.f;
    if (flag[q] == 1) {
        int id = idxb[((size_t)b << 12) + q];
        v = x[((size_t)b * 512 + 256 + c) * S + id];
    }
    out[((size_t)b * 768 + 512 + c) * S + q] = v;
}

// ---------------------------------------------------------------------------
extern "C" void kernel_launch(void* const* d_in, const int* in_sizes, int n_in,
                              void* d_out, int out_size, void* d_ws, size_t ws_size,
                              hipStream_t stream) {
    const float* x    = (const float*)d_in[0];
    const int*   flag = (const int*)d_in[2];
    float*       out  = (float*)d_out;

    char* ws = (char*)d_ws;
    int*   cnts  = (int*)(ws);                 // 2 ints
    int*   qlist = (int*)(ws + 1024);          // 16 KB
    int*   klist = (int*)(ws + 17408);         // 16 KB
    float* invn  = (float*)(ws + 33792);       // 128 KB
    int*   idxb  = (int*)(ws + 164864);        // 128 KB
    float* pmax  = (float*)(ws + 295936);      // 1 MB  (8*4096*8)
    int*   pidx  = (int*)(ws + 1344512);       // 1 MB

    hipLaunchKernelGGL(compact,     dim3(1),                        dim3(256), 0, stream, flag, cnts, qlist, klist);
    hipLaunchKernelGGL(invnorm_k,   dim3(S / 4 / 256, NB),          dim3(256), 0, stream, x, invn);
    hipLaunchKernelGGL(pack_f16,    dim3(S / 32, NB),               dim3(256), 0, stream, x, cnts, qlist, out);
    hipLaunchKernelGGL(pack_l16,    dim3(S / 32, NB),               dim3(256), 0, stream, x, cnts, klist, invn, out);
    hipLaunchKernelGGL(argmax_mfma, dim3((S / BM) * KSPLIT, NB),    dim3(256), 0, stream,
                       out, cnts, klist, pmax, pidx);
    hipLaunchKernelGGL(combine,     dim3(S / 256, NB),              dim3(256), 0, stream, cnts, qlist, pmax, pidx, idxb);
    hipLaunchKernelGGL(copy_fl,     dim3((NB * 512 * S / 4) / 256), dim3(256), 0, stream, x, out);
    hipLaunchKernelGGL(scatter_k,   dim3((NB * CH * S) / 256),      dim3(256), 0, stream, x, flag, idxb, out);
}

// Round 8
// 293.435 us; speedup vs baseline: 15.2614x; 1.2052x over previous
//
#include <hip/hip_runtime.h>

#define S    4096
#define CH   256
#define NB   8

#define BM   128
#define BN   64
#define CKC  32
#define KSPLIT 8

#define SFF  256.0f     // F pre-scale (power of 2; argmax-invariant)
#define SLL  1024.0f    // L pre-scale

#define NEG_INF (-3.402823466e38f)

typedef _Float16 half8 __attribute__((ext_vector_type(8)));
typedef float    f32x4 __attribute__((ext_vector_type(4)));

// ---------------------------------------------------------------------------
// out[:, 0:512] = input  (runs AFTER argmax — that slab holds the f16 panels)
__global__ void copy_fl(const float* __restrict__ x, float* __restrict__ out) {
    int i = blockIdx.x * 256 + threadIdx.x;          // float4 index
    const int per_b = 512 * S / 4;
    int b = i / per_b;
    int r = i - b * per_b;
    const float4* src = (const float4*)x;
    float4* dst = (float4*)out;
    dst[(size_t)b * (768 * S / 4) + r] = src[(size_t)b * per_b + r];
}

// ---------------------------------------------------------------------------
__global__ void compact(const int* __restrict__ flag, int* __restrict__ cnts,
                        int* __restrict__ qlist, int* __restrict__ klist) {
    __shared__ int sq[256], sk[256];
    int t = threadIdx.x;
    int base = t * 16;
    int f[16];
    int nq = 0, nk = 0;
    #pragma unroll
    for (int i = 0; i < 16; ++i) {
        f[i] = flag[base + i];
        nq += (f[i] == 1);
        nk += (f[i] == 0);
    }
    sq[t] = nq; sk[t] = nk;
    __syncthreads();
    for (int off = 1; off < 256; off <<= 1) {
        int vq = sq[t], vk = sk[t];
        int aq = (t >= off) ? sq[t - off] : 0;
        int ak = (t >= off) ? sk[t - off] : 0;
        __syncthreads();
        sq[t] = vq + aq; sk[t] = vk + ak;
        __syncthreads();
    }
    int pq = sq[t] - nq;
    int pk = sk[t] - nk;
    #pragma unroll
    for (int i = 0; i < 16; ++i) {
        if (f[i] == 1)      qlist[pq++] = base + i;
        else                klist[pk++] = base + i;
    }
    if (t == 255) { cnts[0] = sq[255]; cnts[1] = sk[255]; }
}

// ---------------------------------------------------------------------------
__global__ void invnorm_k(const float* __restrict__ x, float* __restrict__ invn) {
    int k4 = blockIdx.x * 256 + threadIdx.x;
    int b  = blockIdx.y;
    const float4* base = (const float4*)(x + ((size_t)b * 512 + 256) * S) + k4;
    float4 acc = { 0.f, 0.f, 0.f, 0.f };
    #pragma unroll 8
    for (int c = 0; c < CH; ++c) {
        float4 v = base[(size_t)c * (S / 4)];
        acc.x += v.x * v.x; acc.y += v.y * v.y;
        acc.z += v.z * v.z; acc.w += v.w * v.w;
    }
    float4 r;
    r.x = 1.0f / fmaxf(sqrtf(acc.x), 1e-12f);
    r.y = 1.0f / fmaxf(sqrtf(acc.y), 1e-12f);
    r.z = 1.0f / fmaxf(sqrtf(acc.z), 1e-12f);
    r.w = 1.0f / fmaxf(sqrtf(acc.w), 1e-12f);
    ((float4*)(invn + ((size_t)b << 12)))[k4] = r;
}

// ---------------------------------------------------------------------------
// f16 hi/lo panels, row-major [row][c], in the out[:,0:512] slab per batch:
//   FH | FL | LH | LL, each S*CH f16 (2 MB).
__global__ void pack_f16(const float* __restrict__ x, const int* __restrict__ cnts,
                         const int* __restrict__ qlist, float* __restrict__ out) {
    const int b = blockIdx.y;
    const int A = cnts[0];
    const int bound = (A + BM - 1) & ~(BM - 1);
    const int r = blockIdx.x * 32 + (threadIdx.x >> 3);
    if (r >= bound) return;
    const int cseg = (threadIdx.x & 7) * 32;
    _Float16* pb = (_Float16*)(out + (size_t)b * 768 * S);
    _Float16* FH = pb;
    _Float16* FL = pb + (size_t)S * CH;
    const float* src = x + (size_t)b * 512 * S;
    const int qq = (r < A) ? qlist[r] : -1;
    #pragma unroll
    for (int g = 0; g < 4; ++g) {
        union { _Float16 u[8]; float4 v; } hb, lb;
        #pragma unroll
        for (int j = 0; j < 8; ++j) {
            float v = 0.f;
            if (qq >= 0) v = src[(size_t)(cseg + g * 8 + j) * S + qq] * SFF;
            _Float16 h = (_Float16)v;
            float res = v - (float)h;
            hb.u[j] = h;
            lb.u[j] = (_Float16)res;
        }
        *(float4*)&FH[(size_t)r * CH + cseg + g * 8] = hb.v;
        *(float4*)&FL[(size_t)r * CH + cseg + g * 8] = lb.v;
    }
}

__global__ void pack_l16(const float* __restrict__ x, const int* __restrict__ cnts,
                         const int* __restrict__ klist, const float* __restrict__ invn,
                         float* __restrict__ out) {
    const int b = blockIdx.y;
    const int A = cnts[1];
    const int bound = (A + BN - 1) & ~(BN - 1);
    const int r = blockIdx.x * 32 + (threadIdx.x >> 3);
    if (r >= bound) return;
    const int cseg = (threadIdx.x & 7) * 32;
    _Float16* pb = (_Float16*)(out + (size_t)b * 768 * S);
    _Float16* LH = pb + 2 * (size_t)S * CH;
    _Float16* LL = pb + 3 * (size_t)S * CH;
    const float* src = x + ((size_t)b * 512 + 256) * S;
    int kk = -1; float w = 0.f;
    if (r < A) { kk = klist[r]; w = invn[((size_t)b << 12) + kk] * SLL; }
    #pragma unroll
    for (int g = 0; g < 4; ++g) {
        union { _Float16 u[8]; float4 v; } hb, lb;
        #pragma unroll
        for (int j = 0; j < 8; ++j) {
            float v = 0.f;
            if (kk >= 0) v = src[(size_t)(cseg + g * 8 + j) * S + kk] * w;
            _Float16 h = (_Float16)v;
            float res = v - (float)h;
            hb.u[j] = h;
            lb.u[j] = (_Float16)res;
        }
        *(float4*)&LH[(size_t)r * CH + cseg + g * 8] = hb.v;
        *(float4*)&LL[(size_t)r * CH + cseg + g * 8] = lb.v;
    }
}

// ---------------------------------------------------------------------------
// MFMA argmax GEMM with global_load_lds staging (pre-swizzled global source,
// linear LDS dest). Block 128q x 64k, 4 waves (each 32q x 64k), CK=32 chunks,
// double-buffered 24 KB LDS buffers, one barrier per chunk.
#define LBUF 24576
#define GLDS(SRC, OFF) __builtin_amdgcn_global_load_lds( \
    (const __attribute__((address_space(1))) void*)(SRC), \
    (__attribute__((address_space(3))) void*)(lds + (OFF)), 16, 0, 0)

#define STAGE(LIT) do { \
    GLDS(s0, (LIT) + 0 * 4096 + woff); \
    GLDS(s1, (LIT) + 1 * 4096 + woff); \
    GLDS(s2, (LIT) + 2 * 4096 + woff); \
    GLDS(s3, (LIT) + 3 * 4096 + woff); \
    GLDS(s4, (LIT) + 16384 + 0 * 4096 + woff); \
    GLDS(s5, (LIT) + 16384 + 1 * 4096 + woff); \
} while (0)

#define ADV() do { \
    if ((tn & 7) == 7) { s0 -= 448; s1 -= 448; s2 -= 448; s3 -= 448; \
                         s4 += 32320; s5 += 32320; } \
    else { s0 += 64; s1 += 64; s2 += 64; s3 += 64; s4 += 64; s5 += 64; } \
    ++tn; \
} while (0)

#define FOLD(T) do { \
    const int kb = (kt0 + ((T) >> 3)) * BN; \
    _Pragma("unroll") \
    for (int mt = 0; mt < 2; ++mt) { \
        _Pragma("unroll") \
        for (int r = 0; r < 4; ++r) { \
            const int ix = mt * 4 + r; \
            _Pragma("unroll") \
            for (int nt = 0; nt < 4; ++nt) { \
                int kp = kb + nt * 16 + l15; \
                if (kp < Ak) { \
                    int kk = klist[kp]; \
                    float sv = acc[mt][nt][r]; \
                    if (sv > rm[ix]) { rm[ix] = sv; ri[ix] = kk; } \
                    else if (sv == rm[ix] && kk < ri[ix]) ri[ix] = kk; \
                } \
            } \
        } \
    } \
    _Pragma("unroll") \
    for (int mt = 0; mt < 2; ++mt) { \
        _Pragma("unroll") \
        for (int nt = 0; nt < 4; ++nt) acc[mt][nt] = (f32x4){0.f, 0.f, 0.f, 0.f}; \
    } \
} while (0)

#define CBODY(LIT, T) do { \
    half8 ah0 = *(const half8*)(lds + aoh0 + (LIT)); \
    half8 al0 = *(const half8*)(lds + aol0 + (LIT)); \
    half8 ah1 = *(const half8*)(lds + aoh1 + (LIT)); \
    half8 al1 = *(const half8*)(lds + aol1 + (LIT)); \
    _Pragma("unroll") \
    for (int nt = 0; nt < 4; ++nt) { \
        half8 bh = *(const half8*)(lds + boff_h[nt] + (LIT)); \
        half8 bl = *(const half8*)(lds + boff_l[nt] + (LIT)); \
        acc[0][nt] = __builtin_amdgcn_mfma_f32_16x16x32_f16(ah0, bh, acc[0][nt], 0, 0, 0); \
        acc[1][nt] = __builtin_amdgcn_mfma_f32_16x16x32_f16(ah1, bh, acc[1][nt], 0, 0, 0); \
        acc[0][nt] = __builtin_amdgcn_mfma_f32_16x16x32_f16(ah0, bl, acc[0][nt], 0, 0, 0); \
        acc[1][nt] = __builtin_amdgcn_mfma_f32_16x16x32_f16(ah1, bl, acc[1][nt], 0, 0, 0); \
        acc[0][nt] = __builtin_amdgcn_mfma_f32_16x16x32_f16(al0, bh, acc[0][nt], 0, 0, 0); \
        acc[1][nt] = __builtin_amdgcn_mfma_f32_16x16x32_f16(al1, bh, acc[1][nt], 0, 0, 0); \
    } \
    if (((T) & 7) == 7) FOLD(T); \
} while (0)

__launch_bounds__(256)
__global__ void argmax_mfma(const float* __restrict__ outbuf,
                            const int*  __restrict__ cnts,
                            const int*  __restrict__ klist,
                            float* __restrict__ pmax,
                            int*   __restrict__ pidx) {
    __shared__ __align__(1024) char lds[2 * LBUF];   // 48 KB

    const int Aq    = cnts[0];
    const int Ak    = cnts[1];
    const int b     = blockIdx.y;
    const int split = blockIdx.x & (KSPLIT - 1);
    const int q0    = (blockIdx.x >> 3) * BM;
    if (q0 >= Aq) return;

    const int tid  = threadIdx.x;
    const int lane = tid & 63;
    const int wid  = tid >> 6;
    const int l15  = lane & 15;
    const int l4   = lane >> 4;
    const int woff = wid * 1024;

    const _Float16* pb  = (const _Float16*)(outbuf + (size_t)b * 768 * S);
    const _Float16* FHg = pb;
    const _Float16* FLg = pb + (size_t)S * CH;
    const _Float16* LHg = pb + 2 * (size_t)S * CH;
    const _Float16* LLg = pb + 3 * (size_t)S * CH;

    const int nkt = (Ak + BN - 1) / BN;
    const int kt0 = (nkt * split) / KSPLIT;
    const int kt1 = (nkt * (split + 1)) / KSPLIT;
    const int nchunk = (kt1 - kt0) * 8;

    float rm[8]; int ri[8];
    #pragma unroll
    for (int i = 0; i < 8; ++i) { rm[i] = NEG_INF; ri[i] = 0; }

    // precomputed LDS read byte-offsets (constant across chunks)
    const int arow0 = wid * 32 + l15;
    const int arow1 = arow0 + 16;
    const int aoh0 = arow0 * 128 + ((l4 * 16)        ^ ((arow0 & 7) << 4));
    const int aol0 = arow0 * 128 + (((l4 * 16) + 64) ^ ((arow0 & 7) << 4));
    const int aoh1 = arow1 * 128 + ((l4 * 16)        ^ ((arow1 & 7) << 4));
    const int aol1 = arow1 * 128 + (((l4 * 16) + 64) ^ ((arow1 & 7) << 4));
    int boff_h[4], boff_l[4];
    #pragma unroll
    for (int nt = 0; nt < 4; ++nt) {
        int rowb = nt * 16 + l15;
        int swzb = (rowb & 7) << 4;
        boff_h[nt] = 16384 + rowb * 128 + ((l4 * 16)        ^ swzb);
        boff_l[nt] = 16384 + rowb * 128 + (((l4 * 16) + 64) ^ swzb);
    }

    if (nchunk > 0) {
        // per-thread pre-swizzled global source pointers for the 6 glds slots
        const char *s0, *s1, *s2, *s3, *s4, *s5;
        {
            const int kb0 = kt0 * BN;
            #define FSRC(P) ({ int s_ = (P) * 256 + tid; int row_ = s_ >> 3; \
                int ls_ = (s_ & 7) ^ (row_ & 7); \
                (const char*)(((ls_ < 4) ? FHg : FLg) + (size_t)(q0 + row_) * CH + (ls_ & 3) * 8); })
            #define LSRC(P) ({ int s_ = (P) * 256 + tid; int row_ = s_ >> 3; \
                int ls_ = (s_ & 7) ^ (row_ & 7); \
                (const char*)(((ls_ < 4) ? LHg : LLg) + (size_t)(kb0 + row_) * CH + (ls_ & 3) * 8); })
            s0 = FSRC(0); s1 = FSRC(1); s2 = FSRC(2); s3 = FSRC(3);
            s4 = LSRC(0); s5 = LSRC(1);
            #undef FSRC
            #undef LSRC
        }
        int tn = 0;

        f32x4 acc[2][4];
        #pragma unroll
        for (int mt = 0; mt < 2; ++mt)
            #pragma unroll
            for (int nt = 0; nt < 4; ++nt) acc[mt][nt] = (f32x4){0.f, 0.f, 0.f, 0.f};

        STAGE(0);
        ADV();
        for (int t = 0; t < nchunk; t += 2) {
            __syncthreads();                       // buf0 (chunk t) ready
            if (t + 1 < nchunk) { STAGE(LBUF); ADV(); }
            CBODY(0, t);
            __syncthreads();                       // buf1 (chunk t+1) ready
            if (t + 2 < nchunk) { STAGE(0); ADV(); }
            CBODY(LBUF, t + 1);
        }
    }

    // reduce across the 16 lanes sharing each q-row group
    #pragma unroll
    for (int mt = 0; mt < 2; ++mt) {
        #pragma unroll
        for (int r = 0; r < 4; ++r) {
            const int ix = mt * 4 + r;
            float m = rm[ix]; int id = ri[ix];
            #pragma unroll
            for (int off = 8; off; off >>= 1) {
                float om = __shfl_xor(m, off, 64);
                int   oi = __shfl_xor(id, off, 64);
                if (om > m || (om == m && oi < id)) { m = om; id = oi; }
            }
            if (l15 == 0) {
                int qp = q0 + wid * 32 + mt * 16 + l4 * 4 + r;
                if (qp < Aq) {
                    size_t o = ((size_t)((b << 12) + qp)) * KSPLIT + split;
                    pmax[o] = m;
                    pidx[o] = id;
                }
            }
        }
    }
}

// ---------------------------------------------------------------------------
__global__ void combine(const int* __restrict__ cnts, const int* __restrict__ qlist,
                        const float* __restrict__ pmax, const int* __restrict__ pidx,
                        int* __restrict__ idxb) {
    int qp = blockIdx.x * 256 + threadIdx.x;
    int b  = blockIdx.y;
    if (qp >= cnts[0]) return;
    size_t base = (size_t)((b << 12) + qp) * KSPLIT;
    float m = pmax[base]; int id = pidx[base];
    #pragma unroll
    for (int s = 1; s < KSPLIT; ++s) {
        float om = pmax[base + s]; int oi = pidx[base + s];
        if (om > m) { m = om; id = oi; }
    }
    idxb[((size_t)b << 12) + qlist[qp]] = id;
}

// ---------------------------------------------------------------------------
__global__ void scatter_k(const float* __restrict__ x, const int* __restrict__ flag,
                          const int* __restrict__ idxb, float* __restrict__ out) {
    int e = blockIdx.x * 256 + threadIdx.x;
    int q = e & (S - 1);
    int c = (e >> 12) & 255;
    int b = e >> 20;
    float v = 0.f;
    if (flag[q] == 1) {
        int id = idxb[((size_t)b << 12) + q];
        v = x[((size_t)b * 512 + 256 + c) * S + id];
    }
    out[((size_t)b * 768 + 512 + c) * S + q] = v;
}

// ---------------------------------------------------------------------------
extern "C" void kernel_launch(void* const* d_in, const int* in_sizes, int n_in,
                              void* d_out, int out_size, void* d_ws, size_t ws_size,
                              hipStream_t stream) {
    const float* x    = (const float*)d_in[0];
    const int*   flag = (const int*)d_in[2];
    float*       out  = (float*)d_out;

    char* ws = (char*)d_ws;
    int*   cnts  = (int*)(ws);                 // 2 ints
    int*   qlist = (int*)(ws + 1024);          // 16 KB
    int*   klist = (int*)(ws + 17408);         // 16 KB
    float* invn  = (float*)(ws + 33792);       // 128 KB
    int*   idxb  = (int*)(ws + 164864);        // 128 KB
    float* pmax  = (float*)(ws + 295936);      // 1 MB  (8*4096*8)
    int*   pidx  = (int*)(ws + 1344512);       // 1 MB

    hipLaunchKernelGGL(compact,     dim3(1),                        dim3(256), 0, stream, flag, cnts, qlist, klist);
    hipLaunchKernelGGL(invnorm_k,   dim3(S / 4 / 256, NB),          dim3(256), 0, stream, x, invn);
    hipLaunchKernelGGL(pack_f16,    dim3(S / 32, NB),               dim3(256), 0, stream, x, cnts, qlist, out);
    hipLaunchKernelGGL(pack_l16,    dim3(S / 32, NB),               dim3(256), 0, stream, x, cnts, klist, invn, out);
    hipLaunchKernelGGL(argmax_mfma, dim3((S / BM) * KSPLIT, NB),    dim3(256), 0, stream,
                       out, cnts, klist, pmax, pidx);
    hipLaunchKernelGGL(combine,     dim3(S / 256, NB),              dim3(256), 0, stream, cnts, qlist, pmax, pidx, idxb);
    hipLaunchKernelGGL(copy_fl,     dim3((NB * 512 * S / 4) / 256), dim3(256), 0, stream, x, out);
    hipLaunchKernelGGL(scatter_k,   dim3((NB * CH * S) / 256),      dim3(256), 0, stream, x, flag, idxb, out);
}